// Round 1
// baseline (101.987 us; speedup 1.0000x reference)
//
#include <hip/hip_runtime.h>
#include <hip/hip_bf16.h>

#ifndef __has_builtin
#define __has_builtin(x) 0
#endif

// ---- problem constants ----
constexpr int B_ = 8, TE_ = 512, TD_ = 128, H_ = 256;
constexpr float TWO_LOG2E = 2.8853900817779268f;   // 2*log2(e)
constexpr float LOG2E = 1.4426950408889634f;

typedef float  vf2    __attribute__((ext_vector_type(2)));
typedef short  bf16x8 __attribute__((ext_vector_type(8)));
typedef float  f32x4  __attribute__((ext_vector_type(4)));

__device__ __forceinline__ float exp2_fast(float x) {
#if __has_builtin(__builtin_amdgcn_exp2f)
  return __builtin_amdgcn_exp2f(x);     // v_exp_f32 (quarter rate)
#else
  return exp2f(x);
#endif
}
__device__ __forceinline__ float rcp_fast(float x) {
#if __has_builtin(__builtin_amdgcn_rcpf)
  return __builtin_amdgcn_rcpf(x);      // v_rcp_f32 (quarter rate)
#else
  return 1.0f / x;
#endif
}
__device__ __forceinline__ vf2 fma2(vf2 a, vf2 b, vf2 c) {
#if __has_builtin(__builtin_elementwise_fma)
  return __builtin_elementwise_fma(a, b, c);   // v_pk_fma_f32
#else
  vf2 r; r.x = __fmaf_rn(a.x, b.x, c.x); r.y = __fmaf_rn(a.y, b.y, c.y); return r;
#endif
}
// split fp32 -> bf16 hi + bf16 lo (x ~= hi + lo to ~2^-16 rel)
__device__ __forceinline__ void bf16split(float x, unsigned short& hi, unsigned short& lo) {
  unsigned u = __float_as_uint(x);
  hi = (unsigned short)(u >> 16);
  float hif = __uint_as_float((unsigned)hi << 16);
  lo = (unsigned short)(__float_as_uint(x - hif) >> 16);
}

// ============== MFMA projection: ep=exp2((enc@W)*2log2e), dp=exp2((dec@U)*2log2e) ==============
// Split-bf16 (3 products). Block tile 32m x 32n, 4 waves, K chunks of 32.
// grid (160, 8) = 1280 blocks. Epilogue exp2 moves the per-score-element exp2
// (134M evals) to the projection (1.6M evals): t = exp2(ep'+dp') = E*D.
__global__ __launch_bounds__(256)
void proj_mfma(const float* __restrict__ enc, const float* __restrict__ dec,
               const float* __restrict__ W, const float* __restrict__ U,
               float* __restrict__ ep, float* __restrict__ dp) {
  __shared__ unsigned short Ah[32][40], Al[32][40], Bh[32][40], Bl[32][40];
  const int tid = threadIdx.x;
  const int mt = blockIdx.x;
  const int n0 = blockIdx.y * 32;
  const float* A; const float* Bm; float* C; int row0;
  if (mt < 128) { A = enc; Bm = W; C = ep; row0 = mt * 32; }
  else          { A = dec; Bm = U; C = dp; row0 = (mt - 128) * 32; }
  const int w = tid >> 6, lane = tid & 63;
  const int mw = (w & 1) * 16, nw = (w >> 1) * 16;
  const int quad = lane >> 4, l16 = lane & 15;
  const int am = tid >> 3, ak = (tid & 7) * 4;
  const int bn = tid & 31, bk = (tid >> 5) * 4;

  f32x4 acc = {0.f, 0.f, 0.f, 0.f};
  for (int k0 = 0; k0 < H_; k0 += 32) {
    float4 a4 = *(const float4*)&A[(long)(row0 + am) * H_ + k0 + ak];
    unsigned short h0, l0, h1, l1, h2, l2, h3, l3;
    bf16split(a4.x, h0, l0); bf16split(a4.y, h1, l1);
    bf16split(a4.z, h2, l2); bf16split(a4.w, h3, l3);
    *(ushort4*)&Ah[am][ak] = make_ushort4(h0, h1, h2, h3);
    *(ushort4*)&Al[am][ak] = make_ushort4(l0, l1, l2, l3);
    float b0 = Bm[(long)(k0 + bk + 0) * H_ + n0 + bn];
    float b1 = Bm[(long)(k0 + bk + 1) * H_ + n0 + bn];
    float b2 = Bm[(long)(k0 + bk + 2) * H_ + n0 + bn];
    float b3 = Bm[(long)(k0 + bk + 3) * H_ + n0 + bn];
    bf16split(b0, h0, l0); bf16split(b1, h1, l1);
    bf16split(b2, h2, l2); bf16split(b3, h3, l3);
    *(ushort4*)&Bh[bn][bk] = make_ushort4(h0, h1, h2, h3);
    *(ushort4*)&Bl[bn][bk] = make_ushort4(l0, l1, l2, l3);
    __syncthreads();
    bf16x8 ah = *(const bf16x8*)&Ah[mw + l16][quad * 8];
    bf16x8 al = *(const bf16x8*)&Al[mw + l16][quad * 8];
    bf16x8 bh = *(const bf16x8*)&Bh[nw + l16][quad * 8];
    bf16x8 bl = *(const bf16x8*)&Bl[nw + l16][quad * 8];
    acc = __builtin_amdgcn_mfma_f32_16x16x32_bf16(ah, bh, acc, 0, 0, 0);
    acc = __builtin_amdgcn_mfma_f32_16x16x32_bf16(ah, bl, acc, 0, 0, 0);
    acc = __builtin_amdgcn_mfma_f32_16x16x32_bf16(al, bh, acc, 0, 0, 0);
    __syncthreads();
  }
#pragma unroll
  for (int r = 0; r < 4; ++r)
    C[(long)(row0 + mw + quad * 4 + r) * H_ + n0 + nw + l16] =
        exp2_fast(acc[r] * TWO_LOG2E);
}

// ================= score kernel v2: t = E*D (no per-elem exp2) =================
// sc_partial[hs][b,d,e] = sum_{h in half} (-2 v_h) * rcp(1 + E[e,h]*D[d,h])
// == tanh-sum minus const shift (invisible to softmax). Exact vs tanh to fp32 rounding.
//
// Register-reuse restructure: block tile 128e x 16d, 256 threads = 4 waves.
// Wave w owns d rows d0+4w..d0+4w+3 (broadcast ds_reads, conflict-free);
// each lane owns e = e0+lane and e0+lane+64 (2 E float4 reads per hh-step).
// LDS instrs per hh-step per wave: 2 E + 4 D + 1 v = 7, covering 128e*4h*4d
// = 2048 elem-computations (293 elems/instr vs 128 before -> 2.3x fewer).
// grid (4, 8, 16) = 512 blocks (2/CU, 39.4 KB LDS each).
__global__ __launch_bounds__(256)
void score_kernel(const float* __restrict__ ep, const float* __restrict__ dp,
                  const float* __restrict__ v, float* __restrict__ sc) {
  __shared__ __align__(16) float eps[128][68];
  __shared__ __align__(16) float dps[16][68];
  __shared__ __align__(16) float vs[64];
  const int tid = threadIdx.x;
  const int bz = blockIdx.z;
  const int b = bz >> 1;
  const int h_lo = (bz & 1) * 128;
  const int e0 = blockIdx.x * 128;
  const int d0 = blockIdx.y * 16;
  const int w = tid >> 6;        // wave id -> d rows d0+4w .. d0+4w+3
  const int lane = tid & 63;     // -> e cols e0+lane, e0+lane+64

  vf2 acc[4][2];
#pragma unroll
  for (int j = 0; j < 4; ++j) {
    acc[j][0] = (vf2){0.f, 0.f};
    acc[j][1] = (vf2){0.f, 0.f};
  }

  for (int h0 = h_lo; h0 < h_lo + 128; h0 += 64) {
    // stage E tile: 128 rows x 64 cols (8 float4 per thread, coalesced 256B runs)
#pragma unroll
    for (int i = 0; i < 8; ++i) {
      int idx = tid + i * 256;
      int r = idx >> 4, c = (idx & 15) << 2;
      *(float4*)&eps[r][c] = *(const float4*)&ep[(long)(b * TE_ + e0 + r) * H_ + h0 + c];
    }
    // stage D tile: 16 rows x 64 cols (1 float4 per thread)
    {
      int r = tid >> 4, c = (tid & 15) << 2;
      *(float4*)&dps[r][c] = *(const float4*)&dp[(long)(b * TD_ + d0 + r) * H_ + h0 + c];
    }
    if (tid < 16) {
      float4 v4 = *(const float4*)&v[h0 + tid * 4];
      float4 o; o.x = -2.f * v4.x; o.y = -2.f * v4.y; o.z = -2.f * v4.z; o.w = -2.f * v4.w;
      *(float4*)&vs[tid * 4] = o;
    }
    __syncthreads();
    const vf2 one2 = {1.f, 1.f};
#pragma unroll 4
    for (int hh = 0; hh < 64; hh += 4) {
      float4 eaf = *(const float4*)&eps[lane][hh];        // E[e0+lane][4h]
      float4 ebf = *(const float4*)&eps[lane + 64][hh];   // E[e0+lane+64][4h]
      float4 vvf = *(const float4*)&vs[hh];               // broadcast
      vf2 ea0 = {eaf.x, eaf.y}, ea1 = {eaf.z, eaf.w};
      vf2 eb0 = {ebf.x, ebf.y}, eb1 = {ebf.z, ebf.w};
      vf2 vv0 = {vvf.x, vvf.y}, vv1 = {vvf.z, vvf.w};
#pragma unroll
      for (int j = 0; j < 4; ++j) {
        float4 df = *(const float4*)&dps[4 * w + j][hh];  // broadcast (wave-uniform)
        vf2 dd0 = {df.x, df.y}, dd1 = {df.z, df.w};
        vf2 t0 = fma2(ea0, dd0, one2);   // v_pk_fma: E*D + 1
        vf2 t1 = fma2(ea1, dd1, one2);
        vf2 u0 = fma2(eb0, dd0, one2);
        vf2 u1 = fma2(eb1, dd1, one2);
        vf2 r0, r1, s0, s1;
        r0.x = rcp_fast(t0.x); r0.y = rcp_fast(t0.y);
        r1.x = rcp_fast(t1.x); r1.y = rcp_fast(t1.y);
        s0.x = rcp_fast(u0.x); s0.y = rcp_fast(u0.y);
        s1.x = rcp_fast(u1.x); s1.y = rcp_fast(u1.y);
        acc[j][0] = fma2(vv0, r0, acc[j][0]); acc[j][0] = fma2(vv1, r1, acc[j][0]);
        acc[j][1] = fma2(vv0, s0, acc[j][1]); acc[j][1] = fma2(vv1, s1, acc[j][1]);
      }
    }
    __syncthreads();
  }
  long rbase = ((long)(bz & 1) * B_ * TD_ + (long)b * TD_ + d0 + 4 * w) * TE_ + e0 + lane;
#pragma unroll
  for (int j = 0; j < 4; ++j) {
    sc[rbase + (long)j * TE_]      = acc[j][0].x + acc[j][0].y;
    sc[rbase + (long)j * TE_ + 64] = acc[j][1].x + acc[j][1].y;
  }
}

// ====== softmax: attn row = softmax(sc_half0 + sc_half1), one wave per row ======
__global__ __launch_bounds__(64)
void softmax_kernel(const float* __restrict__ sc, float* __restrict__ attn) {
  const long row = blockIdx.x;
  const float* p0 = sc + row * TE_;
  const float* p1 = sc + ((long)B_ * TD_ + row) * TE_;
  float* pout = attn + row * TE_;
  const int t = threadIdx.x;
  float x[8];
  float m = -1e30f;
#pragma unroll
  for (int k = 0; k < 8; ++k) {
    x[k] = p0[t + 64 * k] + p1[t + 64 * k];
    m = fmaxf(m, x[k]);
  }
#pragma unroll
  for (int off = 32; off; off >>= 1) m = fmaxf(m, __shfl_xor(m, off, 64));
  float s = 0.f;
#pragma unroll
  for (int k = 0; k < 8; ++k) { x[k] = exp2_fast((x[k] - m) * LOG2E); s += x[k]; }
#pragma unroll
  for (int off = 32; off; off >>= 1) s += __shfl_xor(s, off, 64);
  const float r = rcp_fast(s);
#pragma unroll
  for (int k = 0; k < 8; ++k) pout[t + 64 * k] = x[k] * r;
}

// ================= MFMA context: ctx[b] = attn[b] @ enc[b] =================
// M=128, N=256, K=512 per batch. Block tile 32m x 32n, K chunks of 32.
// grid (4, 8, 8) = 256 blocks. Split-bf16 3-product scheme.
__global__ __launch_bounds__(256)
void ctx_mfma(const float* __restrict__ attn, const float* __restrict__ enc,
              float* __restrict__ ctx) {
  __shared__ unsigned short Ah[32][40], Al[32][40], Bh[32][40], Bl[32][40];
  const int tid = threadIdx.x;
  const int m0 = blockIdx.x * 32;
  const int n0 = blockIdx.y * 32;
  const int b = blockIdx.z;
  const float* A = attn + (long)b * TD_ * TE_;
  const float* E = enc + (long)b * TE_ * H_;
  const int w = tid >> 6, lane = tid & 63;
  const int mw = (w & 1) * 16, nw = (w >> 1) * 16;
  const int quad = lane >> 4, l16 = lane & 15;
  const int am = tid >> 3, ak = (tid & 7) * 4;
  const int bn = tid & 31, bk = (tid >> 5) * 4;

  f32x4 acc = {0.f, 0.f, 0.f, 0.f};
  for (int k0 = 0; k0 < TE_; k0 += 32) {
    float4 a4 = *(const float4*)&A[(long)(m0 + am) * TE_ + k0 + ak];
    unsigned short h0, l0, h1, l1, h2, l2, h3, l3;
    bf16split(a4.x, h0, l0); bf16split(a4.y, h1, l1);
    bf16split(a4.z, h2, l2); bf16split(a4.w, h3, l3);
    *(ushort4*)&Ah[am][ak] = make_ushort4(h0, h1, h2, h3);
    *(ushort4*)&Al[am][ak] = make_ushort4(l0, l1, l2, l3);
    float b0 = E[(long)(k0 + bk + 0) * H_ + n0 + bn];
    float b1 = E[(long)(k0 + bk + 1) * H_ + n0 + bn];
    float b2 = E[(long)(k0 + bk + 2) * H_ + n0 + bn];
    float b3 = E[(long)(k0 + bk + 3) * H_ + n0 + bn];
    bf16split(b0, h0, l0); bf16split(b1, h1, l1);
    bf16split(b2, h2, l2); bf16split(b3, h3, l3);
    *(ushort4*)&Bh[bn][bk] = make_ushort4(h0, h1, h2, h3);
    *(ushort4*)&Bl[bn][bk] = make_ushort4(l0, l1, l2, l3);
    __syncthreads();
    bf16x8 ah = *(const bf16x8*)&Ah[mw + l16][quad * 8];
    bf16x8 al = *(const bf16x8*)&Al[mw + l16][quad * 8];
    bf16x8 bh = *(const bf16x8*)&Bh[nw + l16][quad * 8];
    bf16x8 bl = *(const bf16x8*)&Bl[nw + l16][quad * 8];
    acc = __builtin_amdgcn_mfma_f32_16x16x32_bf16(ah, bh, acc, 0, 0, 0);
    acc = __builtin_amdgcn_mfma_f32_16x16x32_bf16(ah, bl, acc, 0, 0, 0);
    acc = __builtin_amdgcn_mfma_f32_16x16x32_bf16(al, bh, acc, 0, 0, 0);
    __syncthreads();
  }
#pragma unroll
  for (int r = 0; r < 4; ++r)
    ctx[((long)b * TD_ + m0 + mw + quad * 4 + r) * H_ + n0 + nw + l16] = acc[r];
}

extern "C" void kernel_launch(void* const* d_in, const int* in_sizes, int n_in,
                              void* d_out, int out_size, void* d_ws, size_t ws_size,
                              hipStream_t stream) {
  const float* enc = (const float*)d_in[0];  // [B,TE,H]
  const float* dec = (const float*)d_in[1];  // [B,TD,H]
  const float* Wa  = (const float*)d_in[2];  // [H,H]
  const float* Ua  = (const float*)d_in[3];  // [H,H]
  const float* Va  = (const float*)d_in[4];  // [H,1]

  float* out  = (float*)d_out;
  float* ctx  = out;                           // [B,TD,H]
  float* attn = out + (long)B_ * TD_ * H_;     // [B,TD,TE]

  float* ep = (float*)d_ws;                    // [B*TE,H] = exp2(proj*2log2e)
  float* dp = ep + (long)B_ * TE_ * H_;        // [B*TD,H] = exp2(proj*2log2e)
  float* sc = dp + (long)B_ * TD_ * H_;        // [2][B,TD,TE] h-split partials

  proj_mfma<<<dim3(160, 8), 256, 0, stream>>>(enc, dec, Wa, Ua, ep, dp);
  score_kernel<<<dim3(TE_ / 128, TD_ / 16, 2 * B_), 256, 0, stream>>>(ep, dp, Va, sc);
  softmax_kernel<<<dim3(B_ * TD_), 64, 0, stream>>>(sc, attn);
  ctx_mfma<<<dim3(TD_ / 32, H_ / 32, B_), 256, 0, stream>>>(attn, enc, ctx);
}